// Round 1
// baseline (631.461 us; speedup 1.0000x reference)
//
#include <hip/hip_runtime.h>
#include <stdint.h>

// Problem constants
#define BATCH 32
#define C_IN 192
#define T_DIM 256
#define V_N 21
#define HEADS 3
#define C_OUTD 192
#define NPROJ 576        // HEADS*C_OUT
#define NEG_SLOPE 0.2f
#define W_ELEMS (NPROJ * C_IN)   // 110592

typedef __attribute__((ext_vector_type(8))) short short8;
typedef __attribute__((ext_vector_type(4))) float f32x4;

// ---- LDS layout (bytes) ----
// xs: [32][XS_LD] ushort (bf16) staged x slice; aliased later by attnb [3][32][ATTN_LD]
#define XS_LD 200
#define XS_BYTES (32 * XS_LD * 2)            // 12800
#define ATTN_LD 40
#define PROJB_OFF XS_BYTES                   // 12800
#define PROJB_LD 592
#define PROJB_BYTES (32 * PROJB_LD * 2)      // 37888
#define AGG_OFF (PROJB_OFF + PROJB_BYTES)    // 50688
#define AGG_LD 584
#define AGG_BYTES (21 * AGG_LD * 2)          // 24528
#define SS_OFF (AGG_OFF + AGG_BYTES)         // 75216
#define LDS_TOTAL (SS_OFF + 512)             // 75728

__device__ __forceinline__ unsigned short f2bf(float f) {
    uint32_t u = __float_as_uint(f);
    u += 0x7fffu + ((u >> 16) & 1u);   // RNE (inputs are finite)
    return (unsigned short)(u >> 16);
}
__device__ __forceinline__ float bf2f(unsigned short h) {
    return __uint_as_float(((uint32_t)h) << 16);
}

__global__ void convert_w_kernel(const float* __restrict__ W,
                                 unsigned short* __restrict__ Wb, int n) {
    int i = blockIdx.x * 256 + threadIdx.x;
    if (i < n) Wb[i] = f2bf(W[i]);
}

__global__ __launch_bounds__(256)
void gat_fused_kernel(const float* __restrict__ x,
                      const float* __restrict__ A,
                      const float* __restrict__ ssrc,
                      const float* __restrict__ stgt,
                      const unsigned short* __restrict__ Wb,
                      float* __restrict__ out) {
    extern __shared__ char lds[];
    unsigned short* xs    = (unsigned short*)lds;               // [32][XS_LD]
    unsigned short* attnb = (unsigned short*)lds;               // alias: [3][32][ATTN_LD]
    unsigned short* projb = (unsigned short*)(lds + PROJB_OFF); // [32][PROJB_LD]
    unsigned short* aggf  = (unsigned short*)(lds + AGG_OFF);   // [21][AGG_LD]
    float* ssl = (float*)(lds + SS_OFF);        // [21*3]
    float* stl = (float*)(lds + SS_OFF + 256);  // [21*3]

    const int tid  = threadIdx.x;
    const int wv   = tid >> 6;
    const int lane = tid & 63;
    const int q    = lane >> 4;
    const int l15  = lane & 15;
    const int bp   = blockIdx.x;        // bp = b*T + t
    const int b    = bp >> 8;
    const int t    = bp & 255;

    // ---- Stage 1: load x slice -> bf16 LDS; zero projb pad rows (k-pad for agg MFMA)
    const float* xb = x + (size_t)b * (C_IN * T_DIM * V_N) + (size_t)t * V_N;
    for (int idx = tid; idx < V_N * C_IN; idx += 256) {
        int c = idx / V_N;
        int v = idx - c * V_N;
        xs[v * XS_LD + c] = f2bf(xb[(size_t)c * (T_DIM * V_N) + v]);
    }
    for (int idx = tid; idx < 11 * NPROJ; idx += 256) {
        int r = idx / NPROJ;
        int c = idx - r * NPROJ;
        projb[(21 + r) * PROJB_LD + c] = 0;
    }
    __syncthreads();

    // ---- Stage 2: GEMM proj = xs(21x192,pad32) @ Wb^T(192x576)
    // wave wv owns cols [wv*144, wv*144+144); 9 n-tiles of 16; 2 m-tiles; 6 k-steps
    f32x4 acc[9][2];
#pragma unroll
    for (int nt = 0; nt < 9; nt++)
#pragma unroll
        for (int mt = 0; mt < 2; mt++)
            acc[nt][mt] = (f32x4){0.f, 0.f, 0.f, 0.f};

    const int colbase = wv * 144 + l15;
    for (int ks = 0; ks < 6; ks++) {
        const int koff = ks * 32 + q * 8;
        short8 a0 = *(const short8*)(xs + l15 * XS_LD + koff);
        short8 a1 = *(const short8*)(xs + (16 + l15) * XS_LD + koff);
#pragma unroll
        for (int nt = 0; nt < 9; nt++) {
            const int col = colbase + nt * 16;   // W row (output feature)
            short8 bfr = *(const short8*)(Wb + col * C_IN + koff);
            acc[nt][0] = __builtin_amdgcn_mfma_f32_16x16x32_bf16(a0, bfr, acc[nt][0], 0, 0, 0);
            acc[nt][1] = __builtin_amdgcn_mfma_f32_16x16x32_bf16(a1, bfr, acc[nt][1], 0, 0, 0);
        }
    }

    // ---- Stage 3: epilogue -> projb bf16 (rows < 21)
#pragma unroll
    for (int nt = 0; nt < 9; nt++) {
        const int col = colbase + nt * 16;
#pragma unroll
        for (int mt = 0; mt < 2; mt++) {
#pragma unroll
            for (int r = 0; r < 4; r++) {
                int row = mt * 16 + q * 4 + r;   // D layout: row = quad*4 + reg
                if (row < 21) projb[row * PROJB_LD + col] = f2bf(acc[nt][mt][r]);
            }
        }
    }
    __syncthreads();

    // ---- Stage 4: ss/st dots (126 tasks: v x h x {src,tgt})
    if (tid < 126) {
        int v = tid / 6;
        int rem = tid - v * 6;
        int h = rem >> 1;
        int w = rem & 1;
        const float* vec = (w ? stgt : ssrc) + h * C_OUTD;
        const unsigned short* pr = projb + v * PROJB_LD + h * C_OUTD;
        float s = 0.f;
#pragma unroll 8
        for (int c = 0; c < C_OUTD; c++) s += bf2f(pr[c]) * vec[c];
        (w ? stl : ssl)[v * 3 + h] = s;
    }
    __syncthreads();

    // ---- Stage 5: masked softmax per (h, row i) -> attnb bf16 (k-padded with zeros)
    if (tid < 63) {
        int h = tid / 21;
        int i = tid - h * 21;
        const float* Ah = A + h * (V_N * V_N) + i * V_N;
        float si = ssl[i * 3 + h];
        float vals[21];
        float mx = -1e30f;
#pragma unroll
        for (int j = 0; j < 21; j++) {
            float a = Ah[j];
            float z = si + stl[j * 3 + h];
            float e = (z > 0.f) ? z : NEG_SLOPE * z;
            float val = (a != 0.f) ? (e + a) : -1e30f;
            vals[j] = val;
            mx = fmaxf(mx, val);
        }
        float sum = 0.f;
#pragma unroll
        for (int j = 0; j < 21; j++) {
            float e = __expf(vals[j] - mx);
            vals[j] = e;
            sum += e;
        }
        float inv = 1.f / sum;
        unsigned short* arow = attnb + (h * 32 + i) * ATTN_LD;
#pragma unroll
        for (int j = 0; j < 21; j++) arow[j] = f2bf(vals[j] * inv);
#pragma unroll
        for (int j = 21; j < 32; j++) arow[j] = 0;
    }
    __syncthreads();

    // ---- Stage 6: agg[h] = attn[h](21x21,pad32) @ nf[h](21x192,pad32) via MFMA
    // 36 (h,nt) pairs over 4 waves
#pragma unroll
    for (int i = 0; i < 9; i++) {
        int p = wv * 9 + i;
        int h = p / 12;
        int nt = p - h * 12;
        int col = h * C_OUTD + nt * 16 + l15;
        short8 bfr;
#pragma unroll
        for (int j = 0; j < 8; j++)
            bfr[j] = (short)projb[(q * 8 + j) * PROJB_LD + col];
        short8 a0 = *(const short8*)(attnb + (h * 32 + l15) * ATTN_LD + q * 8);
        short8 a1 = *(const short8*)(attnb + (h * 32 + 16 + l15) * ATTN_LD + q * 8);
        f32x4 z = (f32x4){0.f, 0.f, 0.f, 0.f};
        f32x4 d0 = __builtin_amdgcn_mfma_f32_16x16x32_bf16(a0, bfr, z, 0, 0, 0);
        f32x4 d1 = __builtin_amdgcn_mfma_f32_16x16x32_bf16(a1, bfr, z, 0, 0, 0);
#pragma unroll
        for (int r = 0; r < 4; r++) {
            int row0 = q * 4 + r;
            aggf[row0 * AGG_LD + col] = f2bf(d0[r]);
            int row1 = 16 + q * 4 + r;
            if (row1 < 21) aggf[row1 * AGG_LD + col] = f2bf(d1[r]);
        }
    }
    __syncthreads();

    // ---- Stage 7: skip + mean epilogue, torch-faithful regrouping
    // out row n = bp*21 + k; k = h*7 + m; out = mean_j( agg[h][3m+j][c] + proj[k][j][c] )
    float* outb = out + (size_t)bp * (V_N * C_OUTD);
    for (int idx = tid; idx < V_N * C_OUTD; idx += 256) {
        int k = idx / C_OUTD;
        int c = idx - k * C_OUTD;
        int h = k / 7;
        int m = k - h * 7;
        float s = 0.f;
#pragma unroll
        for (int j = 0; j < 3; j++) {
            s += bf2f(aggf[(3 * m + j) * AGG_LD + h * C_OUTD + c]);
            s += bf2f(projb[k * PROJB_LD + j * C_OUTD + c]);
        }
        outb[idx] = s * (1.f / 3.f);
    }
}

extern "C" void kernel_launch(void* const* d_in, const int* in_sizes, int n_in,
                              void* d_out, int out_size, void* d_ws, size_t ws_size,
                              hipStream_t stream) {
    (void)in_sizes; (void)n_in; (void)out_size; (void)ws_size;
    const float* x    = (const float*)d_in[0];
    const float* A    = (const float*)d_in[1];
    const float* W    = (const float*)d_in[2];
    const float* ssrc = (const float*)d_in[3];
    const float* stgt = (const float*)d_in[4];
    float* out = (float*)d_out;
    unsigned short* Wb = (unsigned short*)d_ws;   // 221184 bytes

    convert_w_kernel<<<(W_ELEMS + 255) / 256, 256, 0, stream>>>(W, Wb, W_ELEMS);

    // allow >64KB dynamic LDS (idempotent, capture-safe)
    hipFuncSetAttribute(reinterpret_cast<const void*>(gat_fused_kernel),
                        hipFuncAttributeMaxDynamicSharedMemorySize, LDS_TOTAL);

    gat_fused_kernel<<<BATCH * T_DIM, 256, LDS_TOTAL, stream>>>(x, A, ssrc, stgt, Wb, out);
}

// Round 2
// 597.930 us; speedup vs baseline: 1.0561x; 1.0561x over previous
//
#include <hip/hip_runtime.h>
#include <stdint.h>

// Problem constants
#define BATCH 32
#define C_IN 192
#define T_DIM 256
#define V_N 21
#define HEADS 3
#define C_OUTD 192
#define NPROJ 576        // HEADS*C_OUT
#define NEG_SLOPE 0.2f
#define W_ELEMS (NPROJ * C_IN)   // 110592

typedef __attribute__((ext_vector_type(8))) short short8;
typedef __attribute__((ext_vector_type(4))) float f32x4;

// ---- LDS layout (bytes) ----
// xs region [0, 12800): staged x bf16 [32][XS_LD]; after GEMM it is dead and
// aliased by attnb (float [3][21][22] = 5544 B) and attn2 (bf16 [3][16][40] = 3840 B).
#define XS_LD 200
#define XS_BYTES (32 * XS_LD * 2)        // 12800
#define ATTNB_LD 22
#define ATTN2_OFF 5568                   // 16B aligned, within xs region
#define ATTN2_LD 40
#define PROJB_OFF XS_BYTES               // 12800
#define PROJB_LD 600                     // row = 1200 B (16B aligned, breaks mod-32 quad collisions)
#define PROJB_BYTES (21 * PROJB_LD * 2)  // 25200
#define SS_OFF (PROJB_OFF + PROJB_BYTES) // 38000
#define LDS_TOTAL (SS_OFF + 512)         // 38512  -> 4 blocks/CU

__device__ __forceinline__ unsigned short f2bf(float f) {
    uint32_t u = __float_as_uint(f);
    u += 0x7fffu + ((u >> 16) & 1u);   // RNE (inputs are finite)
    return (unsigned short)(u >> 16);
}
__device__ __forceinline__ float bf2f(unsigned short h) {
    return __uint_as_float(((uint32_t)h) << 16);
}

__global__ void convert_w_kernel(const float* __restrict__ W,
                                 unsigned short* __restrict__ Wb, int n) {
    int i = blockIdx.x * 256 + threadIdx.x;
    if (i < n) Wb[i] = f2bf(W[i]);
}

__global__ __launch_bounds__(256)
void gat_fused_kernel(const float* __restrict__ x,
                      const float* __restrict__ A,
                      const float* __restrict__ ssrc,
                      const float* __restrict__ stgt,
                      const unsigned short* __restrict__ Wb,
                      float* __restrict__ out) {
    __shared__ __align__(16) char lds[LDS_TOTAL];
    unsigned short* xs    = (unsigned short*)lds;               // [32][XS_LD]
    float*          attnb = (float*)lds;                        // alias: [3][21][ATTNB_LD]
    unsigned short* attn2 = (unsigned short*)(lds + ATTN2_OFF); // alias: [3][16][ATTN2_LD]
    unsigned short* projb = (unsigned short*)(lds + PROJB_OFF); // [21][PROJB_LD]
    float* ssl = (float*)(lds + SS_OFF);        // [63]
    float* stl = (float*)(lds + SS_OFF + 256);  // [63]

    const int tid  = threadIdx.x;
    const int wv   = tid >> 6;
    const int lane = tid & 63;
    const int q    = lane >> 4;
    const int l15  = lane & 15;
    const int bp   = blockIdx.x;        // bp = b*T + t
    const int b    = bp >> 8;
    const int t    = bp & 255;

    // ---- Phase A: stage x slice -> bf16 LDS. Issue all 16 loads first (MLP), then convert+store.
    const float* xb = x + (size_t)b * (C_IN * T_DIM * V_N) + (size_t)t * V_N;
    float xr[16];
    int cs[16], vs[16];
#pragma unroll
    for (int k = 0; k < 16; k++) {
        int idx = tid + k * 256;
        int c = idx / 21;
        int v = idx - c * 21;
        cs[k] = c; vs[k] = v;
        xr[k] = (idx < V_N * C_IN) ? xb[c * (T_DIM * V_N) + v] : 0.f;
    }
#pragma unroll
    for (int k = 0; k < 16; k++) {
        int idx = tid + k * 256;
        if (idx < V_N * C_IN) xs[vs[k] * XS_LD + cs[k]] = f2bf(xr[k]);
    }
    __syncthreads();

    // ---- Phase B: GEMM proj = xs(21x192, m-pad 32) @ Wb^T(192x576)
    // wave wv owns cols [wv*144, wv*144+144); 9 n-tiles; 2 m-tiles; 6 k-steps
    f32x4 acc[9][2];
#pragma unroll
    for (int nt = 0; nt < 9; nt++)
#pragma unroll
        for (int mt = 0; mt < 2; mt++)
            acc[nt][mt] = (f32x4){0.f, 0.f, 0.f, 0.f};

    const int colbase = wv * 144 + l15;
    const unsigned short* wb0 = Wb + (size_t)colbase * C_IN;
#pragma unroll
    for (int ks = 0; ks < 6; ks++) {
        const int koff = ks * 32 + q * 8;
        short8 a0 = *(const short8*)(xs + l15 * XS_LD + koff);
        short8 a1 = *(const short8*)(xs + (16 + l15) * XS_LD + koff);  // rows>=21 garbage; D rows discarded
#pragma unroll
        for (int nt = 0; nt < 9; nt++) {
            short8 bfr = *(const short8*)(wb0 + nt * 16 * C_IN + koff);
            acc[nt][0] = __builtin_amdgcn_mfma_f32_16x16x32_bf16(a0, bfr, acc[nt][0], 0, 0, 0);
            acc[nt][1] = __builtin_amdgcn_mfma_f32_16x16x32_bf16(a1, bfr, acc[nt][1], 0, 0, 0);
        }
    }

    // epilogue -> projb bf16 (21 rows only; no k-pad rows, stage-F clamps)
#pragma unroll
    for (int nt = 0; nt < 9; nt++) {
        const int col = colbase + nt * 16;
#pragma unroll
        for (int r = 0; r < 4; r++) {
            int row0 = q * 4 + r;                 // 0..15, always valid
            projb[row0 * PROJB_LD + col] = f2bf(acc[nt][0][r]);
            int row1 = 16 + q * 4 + r;
            if (row1 < 21) projb[row1 * PROJB_LD + col] = f2bf(acc[nt][1][r]);
        }
    }
    __syncthreads();

    // ---- Phase C: ss/st dots, vectorized (126 tasks: v x h x {src,tgt})
    if (tid < 126) {
        int v = tid / 6;
        int rem = tid - v * 6;
        int h = rem >> 1;
        int w = rem & 1;
        const f32x4* vec = (const f32x4*)((w ? stgt : ssrc) + h * C_OUTD);
        const unsigned short* pr = projb + v * PROJB_LD + h * C_OUTD;
        float a0 = 0.f, a1 = 0.f, a2 = 0.f, a3 = 0.f;
#pragma unroll
        for (int cc = 0; cc < C_OUTD; cc += 8) {
            short8 p = *(const short8*)(pr + cc);
            f32x4 v0 = vec[cc >> 2];
            f32x4 v1 = vec[(cc >> 2) + 1];
            a0 += bf2f(p[0]) * v0[0] + bf2f(p[4]) * v1[0];
            a1 += bf2f(p[1]) * v0[1] + bf2f(p[5]) * v1[1];
            a2 += bf2f(p[2]) * v0[2] + bf2f(p[6]) * v1[2];
            a3 += bf2f(p[3]) * v0[3] + bf2f(p[7]) * v1[3];
        }
        float s = (a0 + a1) + (a2 + a3);
        (w ? stl : ssl)[v * 3 + h] = s;
    }
    __syncthreads();

    // ---- Phase D: masked softmax per (h, row i) -> attnb float (xs region is dead now)
    if (tid < 63) {
        int h = tid / 21;
        int i = tid - h * 21;
        const float* Ah = A + h * (V_N * V_N) + i * V_N;
        float si = ssl[i * 3 + h];
        float vals[21];
        float mx = -1e30f;
#pragma unroll
        for (int j = 0; j < 21; j++) {
            float a = Ah[j];
            float z = si + stl[j * 3 + h];
            float e = (z > 0.f) ? z : NEG_SLOPE * z;
            float val = (a != 0.f) ? (e + a) : -1e30f;
            vals[j] = val;
            mx = fmaxf(mx, val);
        }
        float sum = 0.f;
#pragma unroll
        for (int j = 0; j < 21; j++) {
            float e = __expf(vals[j] - mx);
            vals[j] = e;
            sum += e;
        }
        float inv = 1.f / sum;
        float* arow = attnb + (h * 21 + i) * ATTNB_LD;
#pragma unroll
        for (int j = 0; j < 21; j++) arow[j] = vals[j] * inv;
    }
    __syncthreads();

    // ---- Phase E: fold skip-mean's 3-row sum into attention: attn2[h][m][:] = sum of attn rows 3m..3m+2
    if (tid < 48) {
        int h = tid >> 4, m = tid & 15;
        unsigned short* drow = attn2 + (h * 16 + m) * ATTN2_LD;
        if (m < 7) {
            const float* r0 = attnb + (h * 21 + 3 * m) * ATTNB_LD;
#pragma unroll
            for (int j = 0; j < 21; j++)
                drow[j] = f2bf(r0[j] + r0[ATTNB_LD + j] + r0[2 * ATTNB_LD + j]);
#pragma unroll
            for (int j = 21; j < 32; j++) drow[j] = 0;   // k-pad: zero so B pad rows can be clamped data
        } else {
#pragma unroll
            for (int j = 0; j < 32; j++) drow[j] = 0;    // m-pad rows finite
        }
    }
    __syncthreads();

    // ---- Phase F: agg2[h] = attn2[h](7x21 pad 16x32) @ nf[h](21x192) via MFMA, epilogue fused.
    // 36 (h,nt) tasks, 9 per wave, 1 MFMA each.
    float* outb = out + (size_t)bp * (V_N * C_OUTD);
#pragma unroll
    for (int i = 0; i < 9; i++) {
        int p = wv * 9 + i;
        int h = p / 12;
        int nt = p - h * 12;
        int colh = nt * 16 + l15;            // col within head's 192
        int col = h * C_OUTD + colh;         // col within projb's 576
        short8 bfr;
#pragma unroll
        for (int j = 0; j < 8; j++) {
            int row = q * 8 + j;
            if (row > 20) row = 20;          // clamp: attn2 k-cols >=21 are zero
            bfr[j] = (short)projb[row * PROJB_LD + col];
        }
        short8 av = *(const short8*)(attn2 + (h * 16 + l15) * ATTN2_LD + q * 8);
        f32x4 z = (f32x4){0.f, 0.f, 0.f, 0.f};
        f32x4 d = __builtin_amdgcn_mfma_f32_16x16x32_bf16(av, bfr, z, 0, 0, 0);
#pragma unroll
        for (int r = 0; r < 4; r++) {
            int m = q * 4 + r;
            if (m < 7) {
                int k = h * 7 + m;
                float skip = bf2f(projb[k * PROJB_LD + colh])
                           + bf2f(projb[k * PROJB_LD + C_OUTD + colh])
                           + bf2f(projb[k * PROJB_LD + 2 * C_OUTD + colh]);
                outb[k * C_OUTD + colh] = (d[r] + skip) * (1.f / 3.f);
            }
        }
    }
}

extern "C" void kernel_launch(void* const* d_in, const int* in_sizes, int n_in,
                              void* d_out, int out_size, void* d_ws, size_t ws_size,
                              hipStream_t stream) {
    (void)in_sizes; (void)n_in; (void)out_size; (void)ws_size;
    const float* x    = (const float*)d_in[0];
    const float* A    = (const float*)d_in[1];
    const float* W    = (const float*)d_in[2];
    const float* ssrc = (const float*)d_in[3];
    const float* stgt = (const float*)d_in[4];
    float* out = (float*)d_out;
    unsigned short* Wb = (unsigned short*)d_ws;   // 221184 bytes

    convert_w_kernel<<<(W_ELEMS + 255) / 256, 256, 0, stream>>>(W, Wb, W_ELEMS);
    gat_fused_kernel<<<BATCH * T_DIM, 256, 0, stream>>>(x, A, ssrc, stgt, Wb, out);
}

// Round 3
// 572.272 us; speedup vs baseline: 1.1034x; 1.0448x over previous
//
#include <hip/hip_runtime.h>
#include <stdint.h>

// Problem constants
#define BATCH 32
#define C_IN 192
#define T_DIM 256
#define V_N 21
#define HEADS 3
#define C_OUTD 192
#define NPROJ 576        // HEADS*C_OUT
#define NEG_SLOPE 0.2f
#define W_ELEMS (NPROJ * C_IN)   // 110592

typedef __attribute__((ext_vector_type(8))) short short8;
typedef __attribute__((ext_vector_type(4))) float f32x4;

// ---- LDS layout (bytes) ----
#define XS_LD 200
#define XS_BYTES (32 * XS_LD * 2)        // 12800
#define ATTNB_LD 22
#define ATTN2_OFF 5568                   // 16B aligned, within xs region
#define ATTN2_LD 40
#define PROJB_OFF XS_BYTES               // 12800
#define PROJB_LD 600                     // row = 1200 B
#define PROJB_BYTES (21 * PROJB_LD * 2)  // 25200
#define SS_OFF (PROJB_OFF + PROJB_BYTES) // 38000
#define LDS_TOTAL (SS_OFF + 512)         // 38512

__device__ __forceinline__ unsigned short f2bf(float f) {
    uint32_t u = __float_as_uint(f);
    u += 0x7fffu + ((u >> 16) & 1u);   // RNE (inputs are finite)
    return (unsigned short)(u >> 16);
}
__device__ __forceinline__ float bf2f(unsigned short h) {
    return __uint_as_float(((uint32_t)h) << 16);
}

// W (float [576][192]) -> Wf (bf16, MFMA B-fragment order):
// Wf[((nt*6+ks)*64 + lane)*8 + j] = W[nt*16 + (lane&15)][ks*32 + (lane>>4)*8 + j]
__global__ void convert_wf_kernel(const float* __restrict__ W,
                                  unsigned short* __restrict__ Wf) {
    int o = blockIdx.x * 256 + threadIdx.x;   // element index, 110592 total
    if (o >= W_ELEMS) return;
    int j    = o & 7;
    int lane = (o >> 3) & 63;
    int p    = o >> 9;            // 0..215
    int ks   = p % 6;
    int nt   = p / 6;             // 0..35
    int n = nt * 16 + (lane & 15);
    int k = ks * 32 + (lane >> 4) * 8 + j;
    Wf[o] = f2bf(W[n * C_IN + k]);
}

__global__ __launch_bounds__(256)
void gat_fused_kernel(const float* __restrict__ x,
                      const float* __restrict__ A,
                      const float* __restrict__ ssrc,
                      const float* __restrict__ stgt,
                      const unsigned short* __restrict__ Wf,
                      float* __restrict__ out) {
    __shared__ __align__(16) char lds[LDS_TOTAL];
    unsigned short* xs    = (unsigned short*)lds;               // [32][XS_LD]
    float*          attnb = (float*)lds;                        // alias: [3][21][ATTNB_LD]
    unsigned short* attn2 = (unsigned short*)(lds + ATTN2_OFF); // alias: [3][16][ATTN2_LD]
    unsigned short* projb = (unsigned short*)(lds + PROJB_OFF); // [21][PROJB_LD]
    float* ssl = (float*)(lds + SS_OFF);        // [63]
    float* stl = (float*)(lds + SS_OFF + 256);  // [63]

    const int tid  = threadIdx.x;
    const int wv   = tid >> 6;
    const int lane = tid & 63;
    const int q    = lane >> 4;
    const int l15  = lane & 15;
    const int bp   = blockIdx.x;        // bp = b*T + t
    const int b    = bp >> 8;
    const int t    = bp & 255;

    // ---- Phase A: stage x slice -> bf16 LDS. Issue all 16 loads first (MLP), then convert+store.
    const float* xb = x + (size_t)b * (C_IN * T_DIM * V_N) + (size_t)t * V_N;
    float xr[16];
    int cs[16], vs[16];
#pragma unroll
    for (int k = 0; k < 16; k++) {
        int idx = tid + k * 256;
        int c = idx / 21;
        int v = idx - c * 21;
        cs[k] = c; vs[k] = v;
        xr[k] = (idx < V_N * C_IN) ? xb[c * (T_DIM * V_N) + v] : 0.f;
    }
#pragma unroll
    for (int k = 0; k < 16; k++) {
        int idx = tid + k * 256;
        if (idx < V_N * C_IN) xs[vs[k] * XS_LD + cs[k]] = f2bf(xr[k]);
    }
    __syncthreads();

    // ---- Phase B: GEMM proj = xs(21x192, m-pad 32) @ W^T(192x576)
    // wave wv owns cols [wv*144, wv*144+144); 9 n-tiles; 2 m-tiles; 6 k-steps.
    // B-fragments come from Wf in fragment order: fully coalesced 1KB wave reads.
    f32x4 acc[9][2];
#pragma unroll
    for (int nt = 0; nt < 9; nt++)
#pragma unroll
        for (int mt = 0; mt < 2; mt++)
            acc[nt][mt] = (f32x4){0.f, 0.f, 0.f, 0.f};

    const int colbase = wv * 144 + l15;
    const unsigned short* wf0 = Wf + ((size_t)(wv * 9) * 6) * 512 + lane * 8;
#pragma unroll
    for (int ks = 0; ks < 6; ks++) {
        const int koff = ks * 32 + q * 8;
        short8 a0 = *(const short8*)(xs + l15 * XS_LD + koff);
        short8 a1 = *(const short8*)(xs + (16 + l15) * XS_LD + koff);  // rows>=21 garbage; D rows discarded
#pragma unroll
        for (int nt = 0; nt < 9; nt++) {
            short8 bfr = *(const short8*)(wf0 + (nt * 6 + ks) * 512);
            acc[nt][0] = __builtin_amdgcn_mfma_f32_16x16x32_bf16(a0, bfr, acc[nt][0], 0, 0, 0);
            acc[nt][1] = __builtin_amdgcn_mfma_f32_16x16x32_bf16(a1, bfr, acc[nt][1], 0, 0, 0);
        }
    }

    // epilogue -> projb bf16 (21 rows only)
#pragma unroll
    for (int nt = 0; nt < 9; nt++) {
        const int col = colbase + nt * 16;
#pragma unroll
        for (int r = 0; r < 4; r++) {
            int row0 = q * 4 + r;                 // 0..15, always valid
            projb[row0 * PROJB_LD + col] = f2bf(acc[nt][0][r]);
            int row1 = 16 + q * 4 + r;
            if (row1 < 21) projb[row1 * PROJB_LD + col] = f2bf(acc[nt][1][r]);
        }
    }
    __syncthreads();

    // ---- Phase C: ss/st dots, vectorized (126 tasks: v x h x {src,tgt})
    if (tid < 126) {
        int v = tid / 6;
        int rem = tid - v * 6;
        int h = rem >> 1;
        int w = rem & 1;
        const f32x4* vec = (const f32x4*)((w ? stgt : ssrc) + h * C_OUTD);
        const unsigned short* pr = projb + v * PROJB_LD + h * C_OUTD;
        float a0 = 0.f, a1 = 0.f, a2 = 0.f, a3 = 0.f;
#pragma unroll
        for (int cc = 0; cc < C_OUTD; cc += 8) {
            short8 p = *(const short8*)(pr + cc);
            f32x4 v0 = vec[cc >> 2];
            f32x4 v1 = vec[(cc >> 2) + 1];
            a0 += bf2f(p[0]) * v0[0] + bf2f(p[4]) * v1[0];
            a1 += bf2f(p[1]) * v0[1] + bf2f(p[5]) * v1[1];
            a2 += bf2f(p[2]) * v0[2] + bf2f(p[6]) * v1[2];
            a3 += bf2f(p[3]) * v0[3] + bf2f(p[7]) * v1[3];
        }
        float s = (a0 + a1) + (a2 + a3);
        (w ? stl : ssl)[v * 3 + h] = s;
    }
    __syncthreads();

    // ---- Phase D: masked softmax per (h, row i) -> attnb float (xs region dead now)
    if (tid < 63) {
        int h = tid / 21;
        int i = tid - h * 21;
        const float* Ah = A + h * (V_N * V_N) + i * V_N;
        float si = ssl[i * 3 + h];
        float vals[21];
        float mx = -1e30f;
#pragma unroll
        for (int j = 0; j < 21; j++) {
            float a = Ah[j];
            float z = si + stl[j * 3 + h];
            float e = (z > 0.f) ? z : NEG_SLOPE * z;
            float val = (a != 0.f) ? (e + a) : -1e30f;
            vals[j] = val;
            mx = fmaxf(mx, val);
        }
        float sum = 0.f;
#pragma unroll
        for (int j = 0; j < 21; j++) {
            float e = __expf(vals[j] - mx);
            vals[j] = e;
            sum += e;
        }
        float inv = 1.f / sum;
        float* arow = attnb + (h * 21 + i) * ATTNB_LD;
#pragma unroll
        for (int j = 0; j < 21; j++) arow[j] = vals[j] * inv;
    }
    __syncthreads();

    // ---- Phase E: fold skip-mean's 3-row sum into attention
    if (tid < 48) {
        int h = tid >> 4, m = tid & 15;
        unsigned short* drow = attn2 + (h * 16 + m) * ATTN2_LD;
        if (m < 7) {
            const float* r0 = attnb + (h * 21 + 3 * m) * ATTNB_LD;
#pragma unroll
            for (int j = 0; j < 21; j++)
                drow[j] = f2bf(r0[j] + r0[ATTNB_LD + j] + r0[2 * ATTNB_LD + j]);
#pragma unroll
            for (int j = 21; j < 32; j++) drow[j] = 0;
        } else {
#pragma unroll
            for (int j = 0; j < 32; j++) drow[j] = 0;
        }
    }
    __syncthreads();

    // ---- Phase F: agg2[h] = attn2[h](7x21 pad 16x32) @ nf[h](21x192) via MFMA, epilogue fused.
    float* outb = out + (size_t)bp * (V_N * C_OUTD);
#pragma unroll
    for (int i = 0; i < 9; i++) {
        int p = wv * 9 + i;
        int h = p / 12;
        int nt = p - h * 12;
        int colh = nt * 16 + l15;            // col within head's 192
        int col = h * C_OUTD + colh;         // col within projb's 576
        short8 bfr;
#pragma unroll
        for (int j = 0; j < 8; j++) {
            int row = q * 8 + j;
            if (row > 20) row = 20;          // clamp: attn2 k-cols >=21 are zero
            bfr[j] = (short)projb[row * PROJB_LD + col];
        }
        short8 av = *(const short8*)(attn2 + (h * 16 + l15) * ATTN2_LD + q * 8);
        f32x4 z = (f32x4){0.f, 0.f, 0.f, 0.f};
        f32x4 d = __builtin_amdgcn_mfma_f32_16x16x32_bf16(av, bfr, z, 0, 0, 0);
#pragma unroll
        for (int r = 0; r < 4; r++) {
            int m = q * 4 + r;
            if (m < 7) {
                int k = h * 7 + m;
                float skip = bf2f(projb[k * PROJB_LD + colh])
                           + bf2f(projb[k * PROJB_LD + C_OUTD + colh])
                           + bf2f(projb[k * PROJB_LD + 2 * C_OUTD + colh]);
                outb[k * C_OUTD + colh] = (d[r] + skip) * (1.f / 3.f);
            }
        }
    }
}

extern "C" void kernel_launch(void* const* d_in, const int* in_sizes, int n_in,
                              void* d_out, int out_size, void* d_ws, size_t ws_size,
                              hipStream_t stream) {
    (void)in_sizes; (void)n_in; (void)out_size; (void)ws_size;
    const float* x    = (const float*)d_in[0];
    const float* A    = (const float*)d_in[1];
    const float* W    = (const float*)d_in[2];
    const float* ssrc = (const float*)d_in[3];
    const float* stgt = (const float*)d_in[4];
    float* out = (float*)d_out;
    unsigned short* Wf = (unsigned short*)d_ws;   // 221184 bytes

    convert_wf_kernel<<<(W_ELEMS + 255) / 256, 256, 0, stream>>>(W, Wf);
    gat_fused_kernel<<<BATCH * T_DIM, 256, 0, stream>>>(x, A, ssrc, stgt, Wf, out);
}